// Round 15
// baseline (50.202 us; speedup 1.0000x reference)
//
#include <hip/hip_runtime.h>
#include <math.h>

#define NPTS 16384
#define NB   2
#define RCH  512                // refs per block (LDS tile), 16 KiB
#define NRC  (NPTS / RCH)       // 32
#define TILES (RCH / 32)        // 16
#define QPB  128                // queries per block: 4 waves * 1 frag * 32
#define NQC  (NPTS / QPB)       // 128
#define TOTQ (NB * NPTS)        // 32768
#define TOTMIN (2 * TOTQ)       // 65536

typedef short bf16x8 __attribute__((ext_vector_type(8)));

// monotone float <-> uint (t can be negative)
__device__ __forceinline__ unsigned ordf(float f) {
    unsigned b = __float_as_uint(f);
    return (b & 0x80000000u) ? ~b : (b | 0x80000000u);
}
__device__ __forceinline__ float deordf(unsigned u) {
    return __uint_as_float((u & 0x80000000u) ? (u ^ 0x80000000u) : ~u);
}
// bf16 round-to-nearest-even
__device__ __forceinline__ unsigned short bfr(float v) {
    unsigned u = __float_as_uint(v);
    u += 0x7FFFu + ((u >> 16) & 1u);
    return (unsigned short)(u >> 16);
}
__device__ __forceinline__ float ubf(unsigned short h) {
    return __uint_as_float(((unsigned)h) << 16);
}

// async global->LDS, 16B/lane; LDS dest wave-uniform base (+lane*16 in HW)
#define GLD16(gp, lp) __builtin_amdgcn_global_load_lds(                         \
    (const __attribute__((address_space(1))) unsigned int*)(gp),                \
    (__attribute__((address_space(3))) unsigned int*)(lp), 16, 0, 0)

// ---- 1-frag hand-pipelined K-loop: D bank v[48:63], 3 A-buffers v[36:47] ----
#define AB0 "v[36:39]"
#define AB1 "v[40:43]"
#define AB2 "v[44:47]"
#define MF(AB) "v_mfma_f32_32x32x16_bf16 v[48:63], " AB ", %[b0], 0\n\t"
#define RD(AB, OFF) "ds_read_b128 " AB ", %[adr] offset:" OFF "\n\t"
#define W1 "s_waitcnt lgkmcnt(1)\n\t"
#define W0 "s_waitcnt lgkmcnt(0)\n\t"
#define NOPS "s_nop 7\n\ts_nop 7\n\ts_nop 1\n\t"
#define FOLD \
    "v_min3_f32 %[mA], %[mA], v48, v49\n\t" \
    "v_min3_f32 %[mB], %[mB], v50, v51\n\t" \
    "v_min3_f32 %[mA], %[mA], v52, v53\n\t" \
    "v_min3_f32 %[mB], %[mB], v54, v55\n\t" \
    "v_min3_f32 %[mA], %[mA], v56, v57\n\t" \
    "v_min3_f32 %[mB], %[mB], v58, v59\n\t" \
    "v_min3_f32 %[mA], %[mA], v60, v61\n\t" \
    "v_min3_f32 %[mB], %[mB], v62, v63\n\t"
// steady tile: wait cur buf, MFMA, prefetch t+2, nops, fold
#define TS(CUR, PRE, OFF) W1 MF(CUR) RD(PRE, OFF) NOPS FOLD

// K-slot assignment (11 of 16 used):
//  k:      0     1     2     3     4     5     6     7  |  8     9    10   11..15
//  A(ref): rhx   rlx   rhx   rhy   rly   rhy   rhz   rlz|  rhz   wh   wl   0
//  B(qry): -qhx  -qhx  -qlx  -qhy  -qhy  -qly  -qhz  -qhz| -qlz  1.0  1.0  0
// => D = 0.5|r|^2 - q.r  (C = literal 0 in the MFMA)
__global__ __launch_bounds__(256) void prep_kernel(const float* __restrict__ pred,
                                                   const float* __restrict__ target,
                                                   unsigned short* __restrict__ panel,
                                                   unsigned short* __restrict__ qpack,
                                                   float* __restrict__ wq,
                                                   unsigned* __restrict__ mins) {
    int t = blockIdx.x * 256 + threadIdx.x;      // 0..65535
    int cloud = t >> 15, r = t & 32767, b = r >> 14, i = r & 16383;
    const float* src = cloud ? target : pred;
    float x = src[(b * NPTS + i) * 3 + 0];
    float y = src[(b * NPTS + i) * 3 + 1];
    float zz = src[(b * NPTS + i) * 3 + 2];
    float w = 0.5f * (x * x + y * y + zz * zz);

    unsigned short hx = bfr(x),  lx = bfr(x - ubf(hx));
    unsigned short hy = bfr(y),  ly = bfr(y - ubf(hy));
    unsigned short hz = bfr(zz), lz = bfr(zz - ubf(hz));
    unsigned short hw = bfr(w),  lw = bfr(w - ubf(hw));

    const int slot = cloud * 2 + b;

    // A-panel: ref-major, 32B/ref, LDS-linear: ref i -> tile (i>>5), lane (i&31)
    unsigned short* pp = panel + ((size_t)slot << 18) + (size_t)(i >> 5) * 512 + (size_t)(i & 31) * 8;
    uint4 k0, k1;
    k0.x = hx | ((unsigned)lx << 16);
    k0.y = hx | ((unsigned)hy << 16);
    k0.z = ly | ((unsigned)hy << 16);
    k0.w = hz | ((unsigned)lz << 16);
    *(uint4*)pp = k0;
    k1.x = hz | ((unsigned)hw << 16);
    k1.y = lw;
    k1.z = 0; k1.w = 0;
    *(uint4*)(pp + 256) = k1;

    // B-pack: 32B/query, negated split (sign flip is exact)
    const unsigned short S = 0x8000u, ONE = 0x3F80u;
    unsigned short nhx = hx ^ S, nlx = lx ^ S, nhy = hy ^ S, nly = ly ^ S, nhz = hz ^ S, nlz = lz ^ S;
    unsigned short* qp = qpack + ((size_t)slot << 18) + (size_t)i * 16;
    uint4 qlo, qhi;
    qlo.x = nhx | ((unsigned)nhx << 16);
    qlo.y = nlx | ((unsigned)nhy << 16);
    qlo.z = nhy | ((unsigned)nly << 16);
    qlo.w = nhz | ((unsigned)nhz << 16);
    qhi.x = nlz | ((unsigned)ONE << 16);
    qhi.y = ONE;
    qhi.z = 0; qhi.w = 0;
    *(uint4*)qp = qlo;
    *(uint4*)(qp + 8) = qhi;

    wq[(slot << 14) | i] = w;
    mins[(slot << 14) | i] = 0xFFFFFFFFu;
}

// 8 waves/SIMD variant: VGPR <= 64 (launch_bounds 256,8), 16 KiB LDS,
// 1 B-frag per wave, 1 MFMA + 8 min3 per tile.
__global__ __launch_bounds__(256, 8) void nn_min_kernel(const unsigned short* __restrict__ panel,
                                                        const unsigned short* __restrict__ qpack,
                                                        unsigned* __restrict__ mins) {
    __shared__ __attribute__((aligned(16))) unsigned short lds_s[RCH * 16];  // 16 KiB

    const int z = blockIdx.z, b = z & 1, qc = z >> 1, rc = 1 - qc;
    const int tid = threadIdx.x, ln = tid & 63, wv = tid >> 6;

    // ---- stage ref panel chunk (16 KiB) -> LDS via global_load_lds ----
    const char* pbase = (const char*)(panel + (((size_t)(rc * 2 + b)) << 18)
                                      + (size_t)blockIdx.x * (RCH * 16));
    const char* g_ = pbase + wv * 1024 + ln * 16;
    char* l_ = (char*)lds_s + wv * 1024;
    #pragma unroll
    for (int r_ = 0; r_ < 4; ++r_)
        GLD16(g_ + r_ * 4096, l_ + r_ * 4096);

    // ---- B fragment: 1 query-frag of 32 queries per wave ----
    const int qbase = blockIdx.y * QPB;
    const unsigned short* qb = qpack + (((size_t)(qc * 2 + b)) << 18);
    const int qcol = ln & 31, khalf = (ln >> 5) * 8;
    bf16x8 B0 = *(const bf16x8*)(qb + (size_t)(qbase + wv * 32 + qcol) * 16 + khalf);

    asm volatile("s_waitcnt vmcnt(0)" ::: "memory");
    __syncthreads();

    unsigned adr = (unsigned)(unsigned long)
        (__attribute__((address_space(3))) char*)((char*)lds_s + ln * 16);

    float mA = INFINITY, mB = INFINITY;

    // 16-tile K-loop, one asm block; buf rotation t%3; prefetch distance 2.
    asm volatile(
        RD(AB0, "0") RD(AB1, "1024")
        TS(AB0, AB2, "2048")      // t0
        TS(AB1, AB0, "3072")      // t1
        TS(AB2, AB1, "4096")      // t2
        TS(AB0, AB2, "5120")      // t3
        TS(AB1, AB0, "6144")      // t4
        TS(AB2, AB1, "7168")      // t5
        TS(AB0, AB2, "8192")      // t6
        TS(AB1, AB0, "9216")      // t7
        TS(AB2, AB1, "10240")     // t8
        TS(AB0, AB2, "11264")     // t9
        TS(AB1, AB0, "12288")     // t10
        TS(AB2, AB1, "13312")     // t11
        TS(AB0, AB2, "14336")     // t12
        TS(AB1, AB0, "15360")     // t13
        W1 MF(AB2) NOPS FOLD      // t14
        W0 MF(AB0) NOPS FOLD      // t15
        : [mA] "+v"(mA), [mB] "+v"(mB)
        : [adr] "v"(adr), [b0] "v"(B0)
        : "memory",
          "v36","v37","v38","v39","v40","v41","v42","v43",
          "v44","v45","v46","v47",
          "v48","v49","v50","v51","v52","v53","v54","v55",
          "v56","v57","v58","v59","v60","v61","v62","v63");

    unsigned* om = mins + ((size_t)z << 14) + qbase;
    atomicMin(&om[wv * 32 + qcol], ordf(fminf(mA, mB)));
}

// d = sqrt(max(0, 2*(0.5|q|^2 + t_min)))
__global__ __launch_bounds__(256) void reduceA_kernel(const unsigned* __restrict__ mins,
                                                      const float* __restrict__ wq,
                                                      float* __restrict__ partials) {
    int base = blockIdx.x * 1024;
    float s = 0.f;
    #pragma unroll
    for (int k = 0; k < 4; ++k) {
        int t = base + k * 256 + threadIdx.x;
        float m = deordf(mins[t]);
        s += sqrtf(fmaxf(0.f, 2.f * (wq[t] + m)));
    }
    #pragma unroll
    for (int off = 32; off; off >>= 1) s += __shfl_down(s, off);
    __shared__ float wsum[4];
    int lane = threadIdx.x & 63, wv = threadIdx.x >> 6;
    if (lane == 0) wsum[wv] = s;
    __syncthreads();
    if (threadIdx.x == 0) partials[blockIdx.x] = wsum[0] + wsum[1] + wsum[2] + wsum[3];
}

__global__ void reduceB_kernel(const float* __restrict__ partials, float* __restrict__ out) {
    float s = partials[threadIdx.x];
    #pragma unroll
    for (int off = 32; off; off >>= 1) s += __shfl_down(s, off);
    if (threadIdx.x == 0) out[0] = s / (float)TOTQ;
}

extern "C" void kernel_launch(void* const* d_in, const int* in_sizes, int n_in,
                              void* d_out, int out_size, void* d_ws, size_t ws_size,
                              hipStream_t stream) {
    const float* pred   = (const float*)d_in[0];
    const float* target = (const float*)d_in[1];
    char* ws = (char*)d_ws;

    unsigned short* panel = (unsigned short*)ws;                              // 2 MiB
    unsigned short* qpack = (unsigned short*)(ws + (size_t)2 * 1024 * 1024);  // 2 MiB
    float*          wq    = (float*)(ws + (size_t)4 * 1024 * 1024);
    unsigned*       mins  = (unsigned*)(ws + (size_t)4 * 1024 * 1024 + 256 * 1024);
    float*       partials = (float*)(ws + (size_t)4 * 1024 * 1024 + 512 * 1024);
    float* out = (float*)d_out;

    prep_kernel<<<TOTMIN / 256, 256, 0, stream>>>(pred, target, panel, qpack, wq, mins);

    dim3 grid(NRC, NQC, 2 * NB);   // 32 x 128 x 4 = 16384 blocks (8/CU resident)
    nn_min_kernel<<<grid, 256, 0, stream>>>(panel, qpack, mins);

    reduceA_kernel<<<64, 256, 0, stream>>>(mins, wq, partials);
    reduceB_kernel<<<1, 64, 0, stream>>>(partials, out);
}